// Round 4
// baseline (501.891 us; speedup 1.0000x reference)
//
#include <hip/hip_runtime.h>
#include <hip/hip_bf16.h>
#include <hip/hip_cooperative_groups.h>

namespace cg = cooperative_groups;

// Problem constants
#define B_SZ 2048
#define NB   2000
#define DB   30
#define KK   20
#define LL   40
#define PP   2

// Blob per (k,p,l) [stride 336 floats], order [k][p][l]:
//   0: W1[16] f32 | 16: b1[16] f32 | 32: b2[16] f32
//  48: b3p[16] f32 (j'>=8 -> 0) | 64: W4f[16] f32 (W4*sigmoid(alpha), j'>=8 -> 0)
//  80: W2A 256 f16 A-frag | 208: W3A 256 f16 A-frag (rows j'>=8 zero)
#define BLOB_F 336

#define GRID_SZ 1024
#define NMQ 16          // phase-B m splits (125 m each)
#define NUNITS_C 2560   // nam units: bb16 x lc4 x p2 x k20

typedef _Float16 f16x4 __attribute__((ext_vector_type(4)));
typedef float    f32x4 __attribute__((ext_vector_type(4)));

__device__ __forceinline__ float sigmoidf_fast(float z) {
    return 1.0f / (1.0f + __expf(-z));
}
__device__ __forceinline__ float eluf(float x) {
    return x > 0.0f ? x : (__expf(x) - 1.0f);
}

union SmemU {
    struct { float smu[LL * DB]; float sr[LL]; } a;   // 1240 f
    struct { float xs[32 * 27]; float ws[25 * LL]; } b; // 864 + 1000 f
    float sw[10 * BLOB_F];                              // 3360 f
};

__global__ __launch_bounds__(256, 4) void fused_kern(
    const float* __restrict__ x, const float* __restrict__ locs,
    const float* __restrict__ mu, const float* __restrict__ r,
    const float* __restrict__ alpha, const float* __restrict__ beta,
    const float* __restrict__ W1, const float* __restrict__ b1,
    const float* __restrict__ W2, const float* __restrict__ b2,
    const float* __restrict__ W3, const float* __restrict__ b3,
    const float* __restrict__ W4, const float* __restrict__ b4,
    float* __restrict__ w_act, float* __restrict__ g_T,
    float* __restrict__ g_part, float* __restrict__ blob,
    float* __restrict__ beta_eff, float* __restrict__ out)
{
    cg::grid_group grid = cg::this_grid();
    __shared__ SmemU sm;
    const int tid  = threadIdx.x;
    const int bidx = blockIdx.x;
    const int vt   = bidx * 256 + tid;

    // ---------------- Phase A: prep + repack + beta_eff + zero partials -----
    {
        const float4 z = {0.0f, 0.0f, 0.0f, 0.0f};
        float4* gp4 = (float4*)g_part;
        for (int j = vt; j < (NMQ * LL * B_SZ) / 4; j += GRID_SZ * 256)
            gp4[j] = z;
    }
    if (bidx < 320) {
        // w_act[m][l] = sigmoid(r[l] - ||loc_m - mu_l||^2)
        for (int t = tid; t < LL * DB; t += 256) sm.a.smu[t] = mu[t];
        if (tid < LL) sm.a.sr[tid] = r[tid];
        __syncthreads();
        if (vt < NB * LL) {
            int m = vt / LL;
            int l = vt - m * LL;
            float kappa = 0.0f;
            #pragma unroll
            for (int d = 0; d < DB; ++d) {
                float diff = locs[m * DB + d] - sm.a.smu[l * DB + d];
                kappa += diff * diff;
            }
            w_act[vt] = sigmoidf_fast(sm.a.sr[l] - kappa);
        }
    } else if (vt >= 81920 && vt < 184320) {
        // repack: one 64-lane wave per blob; blob id = (k*2+p)*40 + l
        int vt2 = vt - 81920;
        int bidb = vt2 >> 6;       // 0..1599
        int t = vt2 & 63;
        int k = bidb / (PP * LL);
        int rem = bidb - k * (PP * LL);
        int p = rem / LL;
        int l = rem - p * LL;
        int iw = (k * LL + l) * PP + p;
        int n = t & 15, q = t >> 4;
        float* o = blob + (size_t)bidb * BLOB_F;
        float aact = sigmoidf_fast(alpha[l * KK + k]);
        if (t < 16) {
            o[t]      = W1[iw * 16 + t];
            o[16 + t] = b1[iw * 16 + t];
            o[32 + t] = b2[iw * 16 + t];
            o[48 + t] = (t < 8) ? b3[iw * 8 + t] : 0.0f;
            o[64 + t] = (t < 8) ? W4[iw * 8 + t] * aact : 0.0f;
        }
        _Float16* w2a = (_Float16*)(o + 80);
        #pragma unroll
        for (int j = 0; j < 4; ++j)
            w2a[t * 4 + j] = (_Float16)W2[iw * 256 + (4 * q + j) * 16 + n];
        _Float16* w3a = (_Float16*)(o + 208);
        #pragma unroll
        for (int j = 0; j < 4; ++j)
            w3a[t * 4 + j] = (n < 8) ? (_Float16)W3[iw * 128 + (4 * q + j) * 8 + n]
                                     : (_Float16)0.0f;
    } else if (vt >= 184320 && vt < 184320 + KK) {
        int k = vt - 184320;
        float s = beta[k];
        for (int l = 0; l < LL; ++l) {
            float a = sigmoidf_fast(alpha[l * KK + k]);
            s += a * (b4[(k * LL + l) * PP + 0] + b4[(k * LL + l) * PP + 1]);
        }
        beta_eff[k] = s;
    }
    grid.sync();

    // ---------------- Phase B: g partials -----------------------------------
    // unit = bidx: bb = bidx>>4 (64 tiles of 32 b), mq = bidx&15 (125 m each)
    {
        int bb = bidx >> 4;
        int mq = bidx & 15;
        int i  = tid & 31;
        int gq = tid >> 5;          // 0..7 -> l in [gq*5, gq*5+5)
        float acc[5] = {0, 0, 0, 0, 0};
        for (int c = 0; c < 5; ++c) {
            int m0 = mq * 125 + c * 25;
            __syncthreads();
            for (int t = tid; t < 32 * 25; t += 256) {
                int ii = t / 25, jj = t - ii * 25;
                sm.b.xs[ii * 27 + jj] = x[(bb * 32 + ii) * NB + m0 + jj];
            }
            {
                const float4* wa4 = (const float4*)(w_act + m0 * LL);
                float4* dst = (float4*)sm.b.ws;
                for (int t = tid; t < 250; t += 256) dst[t] = wa4[t];
            }
            __syncthreads();
            #pragma unroll 5
            for (int m = 0; m < 25; ++m) {
                float xv = sm.b.xs[i * 27 + m];
                const float* wrow = &sm.b.ws[m * LL + gq * 5];
                #pragma unroll
                for (int u = 0; u < 5; ++u)
                    acc[u] = fmaf(xv, wrow[u], acc[u]);
            }
        }
        #pragma unroll
        for (int u = 0; u < 5; ++u)
            g_part[(mq * LL + gq * 5 + u) * B_SZ + bb * 32 + i] = acc[u];
    }
    grid.sync();

    // ---------------- Phase B2: reduce partials + out init ------------------
    for (int j = vt; j < LL * B_SZ; j += GRID_SZ * 256) {
        float s = 0.0f;
        #pragma unroll
        for (int mq = 0; mq < NMQ; ++mq)
            s += g_part[mq * LL * B_SZ + j];
        g_T[j] = s;
    }
    for (int j = vt; j < B_SZ * KK; j += GRID_SZ * 256)
        out[j] = beta_eff[j % KK];
    grid.sync();

    // ---------------- Phase C: NAM via chained MFMA -------------------------
    {
        const int wv = tid >> 6, lane = tid & 63;
        const int n = lane & 15, q = lane >> 4;
        for (int unit = bidx; unit < NUNITS_C; unit += GRID_SZ) {
            int bb = unit & 15;
            int rr = unit >> 4;
            int lc = rr & 3, p = (rr >> 2) & 1, k = rr >> 3;
            __syncthreads();
            {
                const float4* bl4 = (const float4*)blob;
                float4* sw4 = (float4*)sm.sw;
                int base = ((k * PP + p) * LL + lc * 10) * (BLOB_F / 4);
                for (int t = tid; t < 10 * (BLOB_F / 4); t += 256)
                    sw4[t] = bl4[base + t];
            }
            __syncthreads();
            int b0 = bb * 128 + wv * 32 + n;
            float acc0 = 0.0f, acc1 = 0.0f;

            #pragma unroll 1
            for (int u = 0; u < 10; ++u) {
                const float* W = sm.sw + u * BLOB_F;
                f32x4 w1q = *(const f32x4*)(W + q * 4);
                f32x4 b1q = *(const f32x4*)(W + 16 + q * 4);
                f32x4 b2q = *(const f32x4*)(W + 32 + q * 4);
                f32x4 b3q = *(const f32x4*)(W + 48 + q * 4);
                f32x4 w4q = *(const f32x4*)(W + 64 + q * 4);
                f16x4 w2a = *(const f16x4*)((const _Float16*)(W + 80) + lane * 4);
                f16x4 w3a = *(const f16x4*)((const _Float16*)(W + 208) + lane * 4);

                int l = lc * 10 + u;
                float g0 = g_T[l * B_SZ + b0];
                float g1 = g_T[l * B_SZ + b0 + 16];

                // layer 1 (f32) -> f16 B-frag
                f16x4 hb0, hb1;
                #pragma unroll
                for (int j = 0; j < 4; ++j) {
                    hb0[j] = (_Float16)eluf(fmaf(g0, w1q[j], b1q[j]));
                    hb1[j] = (_Float16)eluf(fmaf(g1, w1q[j], b1q[j]));
                }

                // layer 2: D2 = W2T @ H1 + b2 (bias in C operand)
                f32x4 d20 = __builtin_amdgcn_mfma_f32_16x16x16f16(w2a, hb0, b2q, 0, 0, 0);
                f32x4 d21 = __builtin_amdgcn_mfma_f32_16x16x16f16(w2a, hb1, b2q, 0, 0, 0);

                f16x4 hc0, hc1;
                #pragma unroll
                for (int j = 0; j < 4; ++j) {
                    hc0[j] = (_Float16)eluf(d20[j]);
                    hc1[j] = (_Float16)eluf(d21[j]);
                }

                // layer 3: D3 = W3T @ H2 + b3 (bias in C operand)
                f32x4 d30 = __builtin_amdgcn_mfma_f32_16x16x16f16(w3a, hc0, b3q, 0, 0, 0);
                f32x4 d31 = __builtin_amdgcn_mfma_f32_16x16x16f16(w3a, hc1, b3q, 0, 0, 0);

                // layer 4: acc += elu(h3) . W4f   (q>=2 rows are zeroed)
                #pragma unroll
                for (int rj = 0; rj < 4; ++rj) {
                    acc0 = fmaf(eluf(d30[rj]), w4q[rj], acc0);
                    acc1 = fmaf(eluf(d31[rj]), w4q[rj], acc1);
                }
            }

            acc0 += __shfl_xor(acc0, 16, 64);
            acc0 += __shfl_xor(acc0, 32, 64);
            acc1 += __shfl_xor(acc1, 16, 64);
            acc1 += __shfl_xor(acc1, 32, 64);
            if (lane < 16) {
                atomicAdd(&out[b0 * KK + k], acc0);
                atomicAdd(&out[(b0 + 16) * KK + k], acc1);
            }
        }
    }
}

extern "C" void kernel_launch(void* const* d_in, const int* in_sizes, int n_in,
                              void* d_out, int out_size, void* d_ws, size_t ws_size,
                              hipStream_t stream) {
    const float* x     = (const float*)d_in[0];
    const float* locs  = (const float*)d_in[1];
    const float* mu    = (const float*)d_in[2];
    const float* r     = (const float*)d_in[3];
    const float* alpha = (const float*)d_in[4];
    const float* beta  = (const float*)d_in[5];
    const float* W1    = (const float*)d_in[6];
    const float* b1    = (const float*)d_in[7];
    const float* W2    = (const float*)d_in[8];
    const float* b2    = (const float*)d_in[9];
    const float* W3    = (const float*)d_in[10];
    const float* b3    = (const float*)d_in[11];
    const float* W4    = (const float*)d_in[12];
    const float* b4    = (const float*)d_in[13];
    float* out = (float*)d_out;

    float* ws0      = (float*)d_ws;
    float* w_act    = ws0;                                   //   80000 f
    float* g_T      = w_act + NB * LL;                       //   81920 f
    float* g_part   = g_T + LL * B_SZ;                       // 1310720 f
    float* blob     = g_part + (size_t)NMQ * LL * B_SZ;      //  537600 f
    float* beta_eff = blob + (size_t)KK * PP * LL * BLOB_F;  //      20 f

    void* args[] = {
        (void*)&x, (void*)&locs, (void*)&mu, (void*)&r, (void*)&alpha,
        (void*)&beta, (void*)&W1, (void*)&b1, (void*)&W2, (void*)&b2,
        (void*)&W3, (void*)&b3, (void*)&W4, (void*)&b4,
        (void*)&w_act, (void*)&g_T, (void*)&g_part, (void*)&blob,
        (void*)&beta_eff, (void*)&out
    };
    hipLaunchCooperativeKernel((const void*)fused_kern, dim3(GRID_SZ), dim3(256),
                               args, 0, stream);
}

// Round 5
// 146.121 us; speedup vs baseline: 3.4348x; 3.4348x over previous
//
#include <hip/hip_runtime.h>
#include <hip/hip_bf16.h>

// Problem constants
#define B_SZ 2048
#define NB   2000
#define DB   30
#define KK   20
#define LL   40
#define PP   2

// Blob per (k,p,l) [stride 336 floats], order [k][p][l]:
//   0: W1[16] f32 | 16: b1[16] f32 | 32: b2[16] f32
//  48: b3p[16] f32 (j'>=8 -> 0) | 64: W4f[16] f32 (W4*sigmoid(alpha), j'>=8 -> 0)
//  80: W2A 256 f16 A-frag | 208: W3A 256 f16 A-frag (rows j'>=8 zero)
#define BLOB_F 336

#define GRID_K1 880

typedef _Float16 f16x4 __attribute__((ext_vector_type(4)));
typedef float    f32x4 __attribute__((ext_vector_type(4)));

__device__ __forceinline__ float sigmoidf_fast(float z) {
    return 1.0f / (1.0f + __expf(-z));
}
__device__ __forceinline__ float eluf(float x) {
    return x > 0.0f ? x : (__expf(x) - 1.0f);
}

// K1: w_act (blocks 0-319) | repack (320-719) | out-init+beta (720-879)
//     + stripe-zero g_T across all blocks.
__global__ __launch_bounds__(256) void k1_prep(
    const float* __restrict__ locs, const float* __restrict__ mu,
    const float* __restrict__ r, const float* __restrict__ alpha,
    const float* __restrict__ beta,
    const float* __restrict__ W1, const float* __restrict__ b1,
    const float* __restrict__ W2, const float* __restrict__ b2,
    const float* __restrict__ W3, const float* __restrict__ b3,
    const float* __restrict__ W4, const float* __restrict__ b4,
    float* __restrict__ w_act, float* __restrict__ blob,
    float* __restrict__ g_T, float* __restrict__ out)
{
    __shared__ float smem[LL * DB + LL];   // branch A: mu+r; branch C: beta_eff
    const int tid  = threadIdx.x;
    const int bidx = blockIdx.x;
    const int vt   = bidx * 256 + tid;

    // zero g_T (for K2's atomics)
    for (int j = vt; j < LL * B_SZ; j += GRID_K1 * 256) g_T[j] = 0.0f;

    if (bidx < 320) {
        // w_act[m][l] = sigmoid(r[l] - ||loc_m - mu_l||^2)
        for (int t = tid; t < LL * DB; t += 256) smem[t] = mu[t];
        if (tid < LL) smem[LL * DB + tid] = r[tid];
        __syncthreads();
        if (vt < NB * LL) {
            int m = vt / LL;
            int l = vt - m * LL;
            float kappa = 0.0f;
            #pragma unroll
            for (int d = 0; d < DB; ++d) {
                float diff = locs[m * DB + d] - smem[l * DB + d];
                kappa += diff * diff;
            }
            w_act[vt] = sigmoidf_fast(smem[LL * DB + l] - kappa);
        }
    } else if (bidx < 720) {
        // repack: one 64-lane wave per blob; blob id = (k*2+p)*40 + l
        int vt2 = vt - 320 * 256;       // 0..102399
        int bidb = vt2 >> 6;            // 0..1599
        int t = vt2 & 63;
        int k = bidb / (PP * LL);
        int rem = bidb - k * (PP * LL);
        int p = rem / LL;
        int l = rem - p * LL;
        int iw = (k * LL + l) * PP + p;
        int n = t & 15, q = t >> 4;
        float* o = blob + (size_t)bidb * BLOB_F;
        float aact = sigmoidf_fast(alpha[l * KK + k]);
        if (t < 16) {
            o[t]      = W1[iw * 16 + t];
            o[16 + t] = b1[iw * 16 + t];
            o[32 + t] = b2[iw * 16 + t];
            o[48 + t] = (t < 8) ? b3[iw * 8 + t] : 0.0f;
            o[64 + t] = (t < 8) ? W4[iw * 8 + t] * aact : 0.0f;
        }
        _Float16* w2a = (_Float16*)(o + 80);
        #pragma unroll
        for (int j = 0; j < 4; ++j)
            w2a[t * 4 + j] = (_Float16)W2[iw * 256 + (4 * q + j) * 16 + n];
        _Float16* w3a = (_Float16*)(o + 208);
        #pragma unroll
        for (int j = 0; j < 4; ++j)
            w3a[t * 4 + j] = (n < 8) ? (_Float16)W3[iw * 128 + (4 * q + j) * 8 + n]
                                     : (_Float16)0.0f;
    } else {
        // out[b][k] = beta[k] + sum_{l,p} b4[k,l,p]*sigmoid(alpha[l,k])
        if (tid < KK) {
            int k = tid;
            float s = beta[k];
            for (int l = 0; l < LL; ++l) {
                float a = sigmoidf_fast(alpha[l * KK + k]);
                s += a * (b4[(k * LL + l) * PP + 0] + b4[(k * LL + l) * PP + 1]);
            }
            smem[tid] = s;
        }
        __syncthreads();
        int gid = (bidx - 720) * 256 + tid;    // 0..40959
        out[gid] = smem[gid % KK];
    }
}

// K2: g_T[l][b] += sum_m x[b][m] * w_act[m][l]
// 512 blocks = 32 b-tiles (64 b) x 16 m-splits (125 m); atomics into zeroed g_T.
__global__ __launch_bounds__(256) void k2_g(
    const float* __restrict__ x,      // [B][NB]
    const float* __restrict__ w_act,  // [NB][LL]
    float* __restrict__ g_T)          // [LL][B]
{
    __shared__ float xs[64 * 127];    // stride 127: 2-way alias only (free)
    __shared__ float ws[125 * LL];

    int bb = blockIdx.x >> 4;   // 0..31
    int mq = blockIdx.x & 15;   // 0..15
    int tid = threadIdx.x;
    int i = tid & 63;           // local b
    int w = tid >> 6;           // l group: [w*10, w*10+10)

    for (int t = tid; t < 64 * 125; t += 256) {
        int ii = t / 125;
        int jj = t - ii * 125;
        xs[ii * 127 + jj] = x[(bb * 64 + ii) * NB + mq * 125 + jj];
    }
    {
        const float4* wa4 = (const float4*)(w_act + mq * 125 * LL);
        float4* dst = (float4*)ws;
        for (int t = tid; t < 1250; t += 256) dst[t] = wa4[t];
    }
    __syncthreads();

    float acc[10];
    #pragma unroll
    for (int u = 0; u < 10; ++u) acc[u] = 0.0f;

    #pragma unroll 5
    for (int m = 0; m < 125; ++m) {
        float xv = xs[i * 127 + m];
        const float* wrow = &ws[m * LL + w * 10];
        #pragma unroll
        for (int u = 0; u < 10; ++u)
            acc[u] = fmaf(xv, wrow[u], acc[u]);   // wave-uniform addr: broadcast
    }
    #pragma unroll
    for (int u = 0; u < 10; ++u)
        atomicAdd(&g_T[(w * 10 + u) * B_SZ + bb * 64 + i], acc[u]);
}

// K3: NAM via chained MFMA. Hidden states feature-major [j][b]; MFMA C/D layout
// (col=lane&15=b, row=4q+reg=j) == next MFMA's B-operand layout -> no shuffles.
// bid = bb(16) | lc(4)<<4 | p(2)<<6 | k(20)<<7 -> 2560 blocks, 256 threads.
__global__ __launch_bounds__(256) void k3_nam(
    const float* __restrict__ g_T,    // [LL][B]
    const float* __restrict__ blob,   // [K][P][LL][BLOB_F]
    float* __restrict__ out)          // [B][KK]
{
    __shared__ __align__(16) float sw[10 * BLOB_F];

    int bid = blockIdx.x;
    int bb = bid & 15;
    int lc = (bid >> 4) & 3;
    int p  = (bid >> 6) & 1;
    int k  = bid >> 7;
    int tid = threadIdx.x;

    {
        const float4* bl4 = (const float4*)blob;
        float4* sw4 = (float4*)sw;
        int base = ((k * PP + p) * LL + lc * 10) * (BLOB_F / 4);
        for (int t = tid; t < 10 * (BLOB_F / 4); t += 256)
            sw4[t] = bl4[base + t];
    }
    __syncthreads();

    const int wv = tid >> 6, lane = tid & 63;
    const int n = lane & 15, q = lane >> 4;
    int b0 = bb * 128 + wv * 32 + n;
    float acc0 = 0.0f, acc1 = 0.0f;

    #pragma unroll 1
    for (int u = 0; u < 10; ++u) {
        const float* W = sw + u * BLOB_F;
        f32x4 w1q = *(const f32x4*)(W + q * 4);
        f32x4 b1q = *(const f32x4*)(W + 16 + q * 4);
        f32x4 b2q = *(const f32x4*)(W + 32 + q * 4);
        f32x4 b3q = *(const f32x4*)(W + 48 + q * 4);
        f32x4 w4q = *(const f32x4*)(W + 64 + q * 4);
        f16x4 w2a = *(const f16x4*)((const _Float16*)(W + 80) + lane * 4);
        f16x4 w3a = *(const f16x4*)((const _Float16*)(W + 208) + lane * 4);

        int l = lc * 10 + u;
        float g0 = g_T[l * B_SZ + b0];
        float g1 = g_T[l * B_SZ + b0 + 16];

        // layer 1 (f32) -> f16 B-frag: b[j] = h1[i=4q+j][b=n]
        f16x4 hb0, hb1;
        #pragma unroll
        for (int j = 0; j < 4; ++j) {
            hb0[j] = (_Float16)eluf(fmaf(g0, w1q[j], b1q[j]));
            hb1[j] = (_Float16)eluf(fmaf(g1, w1q[j], b1q[j]));
        }

        // layer 2: D2 = W2T @ H1 + b2 (bias in C operand)
        f32x4 d20 = __builtin_amdgcn_mfma_f32_16x16x16f16(w2a, hb0, b2q, 0, 0, 0);
        f32x4 d21 = __builtin_amdgcn_mfma_f32_16x16x16f16(w2a, hb1, b2q, 0, 0, 0);

        f16x4 hc0, hc1;
        #pragma unroll
        for (int j = 0; j < 4; ++j) {
            hc0[j] = (_Float16)eluf(d20[j]);
            hc1[j] = (_Float16)eluf(d21[j]);
        }

        // layer 3: D3 = W3T @ H2 + b3 (bias in C operand; rows j'>=8 zero)
        f32x4 d30 = __builtin_amdgcn_mfma_f32_16x16x16f16(w3a, hc0, b3q, 0, 0, 0);
        f32x4 d31 = __builtin_amdgcn_mfma_f32_16x16x16f16(w3a, hc1, b3q, 0, 0, 0);

        // layer 4: acc += elu(h3) . W4f  (q>=2 rows are zeroed -> contribute 0)
        #pragma unroll
        for (int rj = 0; rj < 4; ++rj) {
            acc0 = fmaf(eluf(d30[rj]), w4q[rj], acc0);
            acc1 = fmaf(eluf(d31[rj]), w4q[rj], acc1);
        }
    }

    acc0 += __shfl_xor(acc0, 16, 64);
    acc0 += __shfl_xor(acc0, 32, 64);
    acc1 += __shfl_xor(acc1, 16, 64);
    acc1 += __shfl_xor(acc1, 32, 64);
    if (lane < 16) {
        atomicAdd(&out[b0 * KK + k], acc0);
        atomicAdd(&out[(b0 + 16) * KK + k], acc1);
    }
}

extern "C" void kernel_launch(void* const* d_in, const int* in_sizes, int n_in,
                              void* d_out, int out_size, void* d_ws, size_t ws_size,
                              hipStream_t stream) {
    const float* x     = (const float*)d_in[0];
    const float* locs  = (const float*)d_in[1];
    const float* mu    = (const float*)d_in[2];
    const float* r     = (const float*)d_in[3];
    const float* alpha = (const float*)d_in[4];
    const float* beta  = (const float*)d_in[5];
    const float* W1    = (const float*)d_in[6];
    const float* b1    = (const float*)d_in[7];
    const float* W2    = (const float*)d_in[8];
    const float* b2    = (const float*)d_in[9];
    const float* W3    = (const float*)d_in[10];
    const float* b3    = (const float*)d_in[11];
    const float* W4    = (const float*)d_in[12];
    const float* b4    = (const float*)d_in[13];
    float* out = (float*)d_out;

    float* ws0   = (float*)d_ws;
    float* w_act = ws0;                              //  80000 f
    float* g_T   = w_act + NB * LL;                  //  81920 f
    float* blob  = g_T + LL * B_SZ;                  // 537600 f

    k1_prep<<<GRID_K1, 256, 0, stream>>>(locs, mu, r, alpha, beta,
                                         W1, b1, W2, b2, W3, b3, W4, b4,
                                         w_act, blob, g_T, out);
    k2_g<<<512, 256, 0, stream>>>(x, w_act, g_T);
    k3_nam<<<2560, 256, 0, stream>>>(g_T, blob, out);
}

// Round 6
// 143.847 us; speedup vs baseline: 3.4890x; 1.0158x over previous
//
#include <hip/hip_runtime.h>
#include <hip/hip_bf16.h>

// Problem constants
#define B_SZ 2048
#define NB   2000
#define DB   30
#define KK   20
#define LL   40
#define PP   2

// Blob per (k,p,l) [stride 336 floats], order [k][p][l]:
//   0: W1[16] f32 | 16: b1[16] f32 | 32: b2[16] f32
//  48: b3p[16] f32 (j'>=8 -> 0) | 64: W4f[16] f32 (W4*sigmoid(alpha), j'>=8 -> 0)
//  80: W2A 256 f16 A-frag | 208: W3A 256 f16 A-frag (rows j'>=8 zero)
#define BLOB_F 336

#define GRID_K1 880

typedef _Float16 f16x4 __attribute__((ext_vector_type(4)));
typedef float    f32x4 __attribute__((ext_vector_type(4)));

__device__ __forceinline__ float sigmoidf_fast(float z) {
    return 1.0f / (1.0f + __expf(-z));
}
__device__ __forceinline__ float eluf(float x) {
    return x > 0.0f ? x : (__expf(x) - 1.0f);
}

// K1: w_act (blocks 0-319) | repack (320-719) | out-init+beta (720-879)
//     + stripe-zero g_T across all blocks.
__global__ __launch_bounds__(256) void k1_prep(
    const float* __restrict__ locs, const float* __restrict__ mu,
    const float* __restrict__ r, const float* __restrict__ alpha,
    const float* __restrict__ beta,
    const float* __restrict__ W1, const float* __restrict__ b1,
    const float* __restrict__ W2, const float* __restrict__ b2,
    const float* __restrict__ W3, const float* __restrict__ b3,
    const float* __restrict__ W4, const float* __restrict__ b4,
    float* __restrict__ w_act, float* __restrict__ blob,
    float* __restrict__ g_T, float* __restrict__ out)
{
    __shared__ float smem[LL * DB + LL];   // branch A: mu+r; branch C: beta_eff
    const int tid  = threadIdx.x;
    const int bidx = blockIdx.x;
    const int vt   = bidx * 256 + tid;

    // zero g_T (for K2's atomics)
    for (int j = vt; j < LL * B_SZ; j += GRID_K1 * 256) g_T[j] = 0.0f;

    if (bidx < 320) {
        // w_act[m][l] = sigmoid(r[l] - ||loc_m - mu_l||^2)
        for (int t = tid; t < LL * DB; t += 256) smem[t] = mu[t];
        if (tid < LL) smem[LL * DB + tid] = r[tid];
        __syncthreads();
        if (vt < NB * LL) {
            int m = vt / LL;
            int l = vt - m * LL;
            float kappa = 0.0f;
            #pragma unroll
            for (int d = 0; d < DB; ++d) {
                float diff = locs[m * DB + d] - smem[l * DB + d];
                kappa += diff * diff;
            }
            w_act[vt] = sigmoidf_fast(smem[LL * DB + l] - kappa);
        }
    } else if (bidx < 720) {
        // repack: one 64-lane wave per blob; blob id = (k*2+p)*40 + l
        int vt2 = vt - 320 * 256;       // 0..102399
        int bidb = vt2 >> 6;            // 0..1599
        int t = vt2 & 63;
        int k = bidb / (PP * LL);
        int rem = bidb - k * (PP * LL);
        int p = rem / LL;
        int l = rem - p * LL;
        int iw = (k * LL + l) * PP + p;
        int n = t & 15, q = t >> 4;
        float* o = blob + (size_t)bidb * BLOB_F;
        float aact = sigmoidf_fast(alpha[l * KK + k]);
        if (t < 16) {
            o[t]      = W1[iw * 16 + t];
            o[16 + t] = b1[iw * 16 + t];
            o[32 + t] = b2[iw * 16 + t];
            o[48 + t] = (t < 8) ? b3[iw * 8 + t] : 0.0f;
            o[64 + t] = (t < 8) ? W4[iw * 8 + t] * aact : 0.0f;
        }
        _Float16* w2a = (_Float16*)(o + 80);
        #pragma unroll
        for (int j = 0; j < 4; ++j)
            w2a[t * 4 + j] = (_Float16)W2[iw * 256 + (4 * q + j) * 16 + n];
        _Float16* w3a = (_Float16*)(o + 208);
        #pragma unroll
        for (int j = 0; j < 4; ++j)
            w3a[t * 4 + j] = (n < 8) ? (_Float16)W3[iw * 128 + (4 * q + j) * 8 + n]
                                     : (_Float16)0.0f;
    } else {
        // out[b][k] = beta[k] + sum_{l,p} b4[k,l,p]*sigmoid(alpha[l,k])
        if (tid < KK) {
            int k = tid;
            float s = beta[k];
            for (int l = 0; l < LL; ++l) {
                float a = sigmoidf_fast(alpha[l * KK + k]);
                s += a * (b4[(k * LL + l) * PP + 0] + b4[(k * LL + l) * PP + 1]);
            }
            smem[tid] = s;
        }
        __syncthreads();
        int gid = (bidx - 720) * 256 + tid;    // 0..40959
        out[gid] = smem[gid % KK];
    }
}

// K2: g_T[l][b] += sum_m x[b][m] * w_act[m][l]
// 512 blocks = 32 b-tiles (64 b) x 16 m-splits (125 m).
// w_act read through the SCALAR pipe: wave-uniform address (readfirstlane)
// -> s_load into SGPRs; inner loop = 1 ds_read_b32 + 10 v_fmac (FMA-bound).
__global__ __launch_bounds__(256) void k2_g(
    const float* __restrict__ x,      // [B][NB]
    const float* __restrict__ w_act,  // [NB][LL]
    float* __restrict__ g_T)          // [LL][B]
{
    __shared__ float xs[64 * 125];    // dword bank stride 125 (odd->2-way, free)

    int bb = blockIdx.x >> 4;   // 0..31
    int mq = blockIdx.x & 15;   // 0..15
    int tid = threadIdx.x;
    int i = tid & 63;           // local b
    int wu = __builtin_amdgcn_readfirstlane(tid >> 6);  // wave-uniform l-group

    // stage x tile [64][125] (coalesced 125-elem runs)
    for (int t = tid; t < 64 * 125; t += 256) {
        int ii = t / 125;
        int jj = t - ii * 125;
        xs[t] = x[(bb * 64 + ii) * NB + mq * 125 + jj];
    }
    __syncthreads();

    const float* wrow = w_act + (mq * 125) * LL + wu * 10;   // uniform base
    const float* xrow = xs + i * 125;

    float acc[10];
    #pragma unroll
    for (int u = 0; u < 10; ++u) acc[u] = 0.0f;

    #pragma unroll 5
    for (int m = 0; m < 125; ++m) {
        float xv = xrow[m];
        #pragma unroll
        for (int u = 0; u < 10; ++u)
            acc[u] = fmaf(xv, wrow[m * LL + u], acc[u]);  // s_load'd w, SGPR src
    }

    #pragma unroll
    for (int u = 0; u < 10; ++u)
        atomicAdd(&g_T[(wu * 10 + u) * B_SZ + bb * 64 + i], acc[u]);
}

// K3: NAM via chained MFMA. Hidden states feature-major [j][b]; MFMA C/D layout
// (col=lane&15=b, row=4q+reg=j) == next MFMA's B-operand layout -> no shuffles.
// bid = bb(16) | lc(4)<<4 | p(2)<<6 | k(20)<<7 -> 2560 blocks, 256 threads.
__global__ __launch_bounds__(256) void k3_nam(
    const float* __restrict__ g_T,    // [LL][B]
    const float* __restrict__ blob,   // [K][P][LL][BLOB_F]
    float* __restrict__ out)          // [B][KK]
{
    __shared__ __align__(16) float sw[10 * BLOB_F];

    int bid = blockIdx.x;
    int bb = bid & 15;
    int lc = (bid >> 4) & 3;
    int p  = (bid >> 6) & 1;
    int k  = bid >> 7;
    int tid = threadIdx.x;

    const int wv = tid >> 6, lane = tid & 63;
    const int n = lane & 15, q = lane >> 4;
    int b0 = bb * 128 + wv * 32 + n;

    // prefetch g for all 10 l's before the staging barrier (latency hoist)
    float gv0[10], gv1[10];
    #pragma unroll
    for (int u = 0; u < 10; ++u) {
        gv0[u] = g_T[(lc * 10 + u) * B_SZ + b0];
        gv1[u] = g_T[(lc * 10 + u) * B_SZ + b0 + 16];
    }

    {
        const float4* bl4 = (const float4*)blob;
        float4* sw4 = (float4*)sw;
        int base = ((k * PP + p) * LL + lc * 10) * (BLOB_F / 4);
        for (int t = tid; t < 10 * (BLOB_F / 4); t += 256)
            sw4[t] = bl4[base + t];
    }
    __syncthreads();

    float acc0 = 0.0f, acc1 = 0.0f;

    #pragma unroll 1
    for (int u = 0; u < 10; ++u) {
        const float* W = sw + u * BLOB_F;
        f32x4 w1q = *(const f32x4*)(W + q * 4);
        f32x4 b1q = *(const f32x4*)(W + 16 + q * 4);
        f32x4 b2q = *(const f32x4*)(W + 32 + q * 4);
        f32x4 b3q = *(const f32x4*)(W + 48 + q * 4);
        f32x4 w4q = *(const f32x4*)(W + 64 + q * 4);
        f16x4 w2a = *(const f16x4*)((const _Float16*)(W + 80) + lane * 4);
        f16x4 w3a = *(const f16x4*)((const _Float16*)(W + 208) + lane * 4);

        float g0 = gv0[u];
        float g1 = gv1[u];

        // layer 1 (f32) -> f16 B-frag: b[j] = h1[i=4q+j][b=n]
        f16x4 hb0, hb1;
        #pragma unroll
        for (int j = 0; j < 4; ++j) {
            hb0[j] = (_Float16)eluf(fmaf(g0, w1q[j], b1q[j]));
            hb1[j] = (_Float16)eluf(fmaf(g1, w1q[j], b1q[j]));
        }

        // layer 2: D2 = W2T @ H1 + b2 (bias in C operand)
        f32x4 d20 = __builtin_amdgcn_mfma_f32_16x16x16f16(w2a, hb0, b2q, 0, 0, 0);
        f32x4 d21 = __builtin_amdgcn_mfma_f32_16x16x16f16(w2a, hb1, b2q, 0, 0, 0);

        f16x4 hc0, hc1;
        #pragma unroll
        for (int j = 0; j < 4; ++j) {
            hc0[j] = (_Float16)eluf(d20[j]);
            hc1[j] = (_Float16)eluf(d21[j]);
        }

        // layer 3: D3 = W3T @ H2 + b3 (bias in C operand; rows j'>=8 zero)
        f32x4 d30 = __builtin_amdgcn_mfma_f32_16x16x16f16(w3a, hc0, b3q, 0, 0, 0);
        f32x4 d31 = __builtin_amdgcn_mfma_f32_16x16x16f16(w3a, hc1, b3q, 0, 0, 0);

        // layer 4: acc += elu(h3) . W4f  (q>=2 rows are zeroed -> contribute 0)
        #pragma unroll
        for (int rj = 0; rj < 4; ++rj) {
            acc0 = fmaf(eluf(d30[rj]), w4q[rj], acc0);
            acc1 = fmaf(eluf(d31[rj]), w4q[rj], acc1);
        }
    }

    acc0 += __shfl_xor(acc0, 16, 64);
    acc0 += __shfl_xor(acc0, 32, 64);
    acc1 += __shfl_xor(acc1, 16, 64);
    acc1 += __shfl_xor(acc1, 32, 64);
    if (lane < 16) {
        atomicAdd(&out[b0 * KK + k], acc0);
        atomicAdd(&out[(b0 + 16) * KK + k], acc1);
    }
}

extern "C" void kernel_launch(void* const* d_in, const int* in_sizes, int n_in,
                              void* d_out, int out_size, void* d_ws, size_t ws_size,
                              hipStream_t stream) {
    const float* x     = (const float*)d_in[0];
    const float* locs  = (const float*)d_in[1];
    const float* mu    = (const float*)d_in[2];
    const float* r     = (const float*)d_in[3];
    const float* alpha = (const float*)d_in[4];
    const float* beta  = (const float*)d_in[5];
    const float* W1    = (const float*)d_in[6];
    const float* b1    = (const float*)d_in[7];
    const float* W2    = (const float*)d_in[8];
    const float* b2    = (const float*)d_in[9];
    const float* W3    = (const float*)d_in[10];
    const float* b3    = (const float*)d_in[11];
    const float* W4    = (const float*)d_in[12];
    const float* b4    = (const float*)d_in[13];
    float* out = (float*)d_out;

    float* ws0   = (float*)d_ws;
    float* w_act = ws0;                              //  80000 f
    float* g_T   = w_act + NB * LL;                  //  81920 f
    float* blob  = g_T + LL * B_SZ;                  // 537600 f

    k1_prep<<<GRID_K1, 256, 0, stream>>>(locs, mu, r, alpha, beta,
                                         W1, b1, W2, b2, W3, b3, W4, b4,
                                         w_act, blob, g_T, out);
    k2_g<<<512, 256, 0, stream>>>(x, w_act, g_T);
    k3_nam<<<2560, 256, 0, stream>>>(g_T, blob, out);
}